// Round 1
// baseline (9726.094 us; speedup 1.0000x reference)
//
#include <hip/hip_runtime.h>
#include <hip/hip_bf16.h>

#define CDIM 192
#define WSZ 7
#define SSZ 3
#define NHEAD 6
#define HD 32
#define NTOK 49          // tokens per window
#define HW 56
#define TTOK (32*56*56)  // 100352 tokens total

// ---------------------------------------------------------------------------
// LayerNorm stats: one wave per token, 4 tokens per 256-thread block.
// ---------------------------------------------------------------------------
__global__ __launch_bounds__(256) void ln_stats_kernel(const float* __restrict__ x,
                                                       float2* __restrict__ stats) {
    int wid  = threadIdx.x >> 6;
    int lane = threadIdx.x & 63;
    int token = blockIdx.x * 4 + wid;
    const float* p = x + (size_t)token * CDIM;
    float a0 = p[lane], a1 = p[lane + 64], a2 = p[lane + 128];
    float s = a0 + a1 + a2;
    float q = a0 * a0 + a1 * a1 + a2 * a2;
    #pragma unroll
    for (int m = 32; m >= 1; m >>= 1) {
        s += __shfl_xor(s, m);
        q += __shfl_xor(q, m);
    }
    if (lane == 0) {
        float mean = s * (1.0f / 192.0f);
        float var  = q * (1.0f / 192.0f) - mean * mean;
        stats[token] = make_float2(mean, rsqrtf(var + 1e-5f));
    }
}

// ---------------------------------------------------------------------------
// Fused shifted-window attention + proj + residual.
// One block (256 threads) per window. 2048 blocks.
// x2 = x + proj(attn(LN1(x) windowed)) at the same (h,w) position
// (roll(-3) into windows and roll(+3) back cancel).
// ---------------------------------------------------------------------------
__global__ __launch_bounds__(256) void attn_kernel(
    const float*  __restrict__ x,
    const float2* __restrict__ stats,
    const float*  __restrict__ g1, const float* __restrict__ b1,
    const float*  __restrict__ qkv_w, const float* __restrict__ qkv_b,
    const float*  __restrict__ rpb,
    const float*  __restrict__ proj_w, const float* __restrict__ proj_b,
    float* __restrict__ x2)
{
    __shared__ __hip_bfloat16 xw[NTOK * CDIM];           // 18816 B
    __shared__ float qs[NTOK * 33];                      // 6468 B (pad 33: bank spread)
    __shared__ float ks[NTOK * 33];
    __shared__ float vs[NTOK * 33];
    __shared__ float sc[NTOK * NTOK];                    // 9604 B
    __shared__ float ho[NTOK * 33];                      // 6468 B
    // total 54292 B -> 2 blocks/CU

    const int bid = blockIdx.x;
    const int b   = bid >> 6;
    const int w   = bid & 63;
    const int wh  = w >> 3, ww = w & 7;
    const int tid = threadIdx.x;

    // ---- gather window (shifted), apply LN1, store bf16 ----
    for (int e = tid; e < NTOK * CDIM; e += 256) {
        int n = e / CDIM, c = e - n * CDIM;
        int i = n / 7, j = n - i * 7;
        int hs = wh * 7 + i + SSZ; if (hs >= HW) hs -= HW;
        int ws = ww * 7 + j + SSZ; if (ws >= HW) ws -= HW;
        int tok = (b * HW + hs) * HW + ws;
        float2 st = stats[tok];
        float v = x[(size_t)tok * CDIM + c];
        xw[n * CDIM + c] = __float2bfloat16((v - st.x) * st.y * g1[c] + b1[c]);
    }
    __syncthreads();

    // proj-output accumulators: thread t<196 owns token pn, channels [pc0, pc0+48)
    float acc[48];
    #pragma unroll
    for (int j = 0; j < 48; j++) acc[j] = 0.0f;
    const int pn  = tid >> 2;
    const int pc0 = (tid & 3) * 48;

    const float scale = 0.17677669529663687f;  // 1/sqrt(32)

    for (int h = 0; h < NHEAD; h++) {
        // ---- q,k,v for this head (q pre-scaled) ----
        for (int e = tid; e < NTOK * HD; e += 256) {
            int n = e >> 5, d = e & 31;
            int cq = h * 32 + d;
            float aq = qkv_b[cq], ak = qkv_b[192 + cq], av = qkv_b[384 + cq];
            const float* wq = qkv_w + cq;
            for (int c = 0; c < CDIM; c++) {
                float xv = __bfloat162float(xw[n * CDIM + c]);
                const float* wr = wq + c * 576;
                aq += xv * wr[0];
                ak += xv * wr[192];
                av += xv * wr[384];
            }
            qs[n * 33 + d] = aq * scale;
            ks[n * 33 + d] = ak;
            vs[n * 33 + d] = av;
        }
        __syncthreads();

        // ---- scores = q.k^T + rpb + shift-mask ----
        for (int e = tid; e < NTOK * NTOK; e += 256) {
            int i = e / 49, j = e - i * 49;
            float a = 0.0f;
            #pragma unroll 8
            for (int d = 0; d < 32; d++) a += qs[i * 33 + d] * ks[j * 33 + d];
            int ih = i / 7, iw = i - ih * 7;
            int jh = j / 7, jw = j - jh * 7;
            a += rpb[((ih - jh + 6) * 13 + (iw - jw + 6)) * NHEAD + h];
            int pi = wh * 7 + ih, qi = ww * 7 + iw;
            int pj = wh * 7 + jh, qj = ww * 7 + jw;
            int ci = (pi < 49 ? 0 : (pi < 53 ? 1 : 2)) * 3 + (qi < 49 ? 0 : (qi < 53 ? 1 : 2));
            int cj = (pj < 49 ? 0 : (pj < 53 ? 1 : 2)) * 3 + (qj < 49 ? 0 : (qj < 53 ? 1 : 2));
            if (ci != cj) a -= 100.0f;
            sc[i * 49 + j] = a;
        }
        __syncthreads();

        // ---- softmax, one row per thread ----
        if (tid < NTOK) {
            float m = -1e30f;
            for (int j = 0; j < 49; j++) m = fmaxf(m, sc[tid * 49 + j]);
            float s = 0.0f;
            for (int j = 0; j < 49; j++) {
                float e = __expf(sc[tid * 49 + j] - m);
                sc[tid * 49 + j] = e;
                s += e;
            }
            float inv = 1.0f / s;
            for (int j = 0; j < 49; j++) sc[tid * 49 + j] *= inv;
        }
        __syncthreads();

        // ---- head_out = attn @ v ----
        for (int e = tid; e < NTOK * HD; e += 256) {
            int n = e >> 5, d = e & 31;
            float a = 0.0f;
            for (int j = 0; j < 49; j++) a += sc[n * 49 + j] * vs[j * 33 + d];
            ho[n * 33 + d] = a;
        }
        __syncthreads();

        // ---- partial proj: acc += head_out @ proj_w[h*32:(h+1)*32, :] ----
        if (tid < 196) {
            const float* wp = proj_w + (size_t)h * 32 * 192 + pc0;
            for (int d = 0; d < 32; d++) {
                float hv = ho[pn * 33 + d];
                const float4* w4 = (const float4*)(wp + (size_t)d * 192);
                #pragma unroll
                for (int j4 = 0; j4 < 12; j4++) {
                    float4 wv = w4[j4];
                    acc[j4 * 4 + 0] += hv * wv.x;
                    acc[j4 * 4 + 1] += hv * wv.y;
                    acc[j4 * 4 + 2] += hv * wv.z;
                    acc[j4 * 4 + 3] += hv * wv.w;
                }
            }
        }
        __syncthreads();
    }

    // ---- x2 = x + proj_out + proj_b (source pos == dest pos) ----
    if (tid < 196) {
        int i = pn / 7, j = pn - i * 7;
        int hs = wh * 7 + i + SSZ; if (hs >= HW) hs -= HW;
        int ws = ww * 7 + j + SSZ; if (ws >= HW) ws -= HW;
        size_t tok = ((size_t)b * HW + hs) * HW + ws;
        const float4* xr = (const float4*)(x + tok * CDIM + pc0);
        const float4* pb = (const float4*)(proj_b + pc0);
        float4* o = (float4*)(x2 + tok * CDIM + pc0);
        #pragma unroll
        for (int j4 = 0; j4 < 12; j4++) {
            float4 xv = xr[j4], bv = pb[j4], ov;
            ov.x = xv.x + bv.x + acc[j4 * 4 + 0];
            ov.y = xv.y + bv.y + acc[j4 * 4 + 1];
            ov.z = xv.z + bv.z + acc[j4 * 4 + 2];
            ov.w = xv.w + bv.w + acc[j4 * 4 + 3];
            o[j4] = ov;
        }
    }
}

// ---------------------------------------------------------------------------
// Fused MLP: out = x2 + fc2(gelu(fc1(LN2(x2)))), hidden chunked by 64.
// 64 tokens per block (256 threads), 1568 blocks.
// ---------------------------------------------------------------------------
__global__ __launch_bounds__(256) void mlp_kernel(
    const float*  __restrict__ x2,
    const float2* __restrict__ stats,
    const float*  __restrict__ g2, const float* __restrict__ b2,
    const float*  __restrict__ fc1_w, const float* __restrict__ fc1_b,
    const float*  __restrict__ fc2_w, const float* __restrict__ fc2_b,
    float* __restrict__ out)
{
    __shared__ __hip_bfloat16 xn[64 * 194];  // 24832 B (pad 194: bank spread)
    __shared__ float hbuf[64 * 66];          // 16896 B (pad 66)

    const int tid = threadIdx.x;
    const size_t tok0 = (size_t)blockIdx.x * 64;

    // ---- load tile + LN2, store bf16 ----
    for (int e = tid; e < 64 * CDIM; e += 256) {
        int n = e / CDIM, c = e - n * CDIM;
        size_t tok = tok0 + n;
        float2 st = stats[tok];
        float v = x2[tok * CDIM + c];
        xn[n * 194 + c] = __float2bfloat16((v - st.x) * st.y * g2[c] + b2[c]);
    }
    __syncthreads();

    const int n   = tid >> 2;
    const int kk0 = (tid & 3) * 16;  // fc1: 16 hidden units
    const int c0  = (tid & 3) * 48;  // fc2: 48 output channels

    float acc[48];
    #pragma unroll
    for (int j = 0; j < 48; j++) acc[j] = 0.0f;

    for (int K0 = 0; K0 < 768; K0 += 64) {
        // ---- fc1 chunk into registers ----
        float ha[16];
        #pragma unroll
        for (int j = 0; j < 16; j++) ha[j] = fc1_b[K0 + kk0 + j];
        for (int c = 0; c < CDIM; c++) {
            float xv = __bfloat162float(xn[n * 194 + c]);
            const float4* w4 = (const float4*)(fc1_w + (size_t)c * 768 + K0 + kk0);
            #pragma unroll
            for (int j4 = 0; j4 < 4; j4++) {
                float4 wv = w4[j4];
                ha[j4 * 4 + 0] += xv * wv.x;
                ha[j4 * 4 + 1] += xv * wv.y;
                ha[j4 * 4 + 2] += xv * wv.z;
                ha[j4 * 4 + 3] += xv * wv.w;
            }
        }
        __syncthreads();  // prior fc2 reads of hbuf complete
        #pragma unroll
        for (int j = 0; j < 16; j++) {
            float v = ha[j];
            hbuf[n * 66 + kk0 + j] = v * 0.5f * (1.0f + erff(v * 0.70710678118654752f));
        }
        __syncthreads();

        // ---- fc2 accumulate ----
        for (int kk = 0; kk < 64; kk++) {
            float hv = hbuf[n * 66 + kk];
            const float4* w4 = (const float4*)(fc2_w + (size_t)(K0 + kk) * CDIM + c0);
            #pragma unroll
            for (int j4 = 0; j4 < 12; j4++) {
                float4 wv = w4[j4];
                acc[j4 * 4 + 0] += hv * wv.x;
                acc[j4 * 4 + 1] += hv * wv.y;
                acc[j4 * 4 + 2] += hv * wv.z;
                acc[j4 * 4 + 3] += hv * wv.w;
            }
        }
    }

    // ---- out = x2 + acc + fc2_b ----
    size_t tok = tok0 + n;
    const float4* xr = (const float4*)(x2 + tok * CDIM + c0);
    const float4* bb = (const float4*)(fc2_b + c0);
    float4* o = (float4*)(out + tok * CDIM + c0);
    #pragma unroll
    for (int j4 = 0; j4 < 12; j4++) {
        float4 xv = xr[j4], bv = bb[j4], ov;
        ov.x = xv.x + bv.x + acc[j4 * 4 + 0];
        ov.y = xv.y + bv.y + acc[j4 * 4 + 1];
        ov.z = xv.z + bv.z + acc[j4 * 4 + 2];
        ov.w = xv.w + bv.w + acc[j4 * 4 + 3];
        o[j4] = ov;
    }
}

// ---------------------------------------------------------------------------
extern "C" void kernel_launch(void* const* d_in, const int* in_sizes, int n_in,
                              void* d_out, int out_size, void* d_ws, size_t ws_size,
                              hipStream_t stream) {
    const float* x      = (const float*)d_in[0];
    const float* g1     = (const float*)d_in[1];
    const float* b1     = (const float*)d_in[2];
    const float* qkv_w  = (const float*)d_in[3];
    const float* qkv_b  = (const float*)d_in[4];
    const float* rpb    = (const float*)d_in[5];
    const float* proj_w = (const float*)d_in[6];
    const float* proj_b = (const float*)d_in[7];
    const float* g2     = (const float*)d_in[8];
    const float* b2     = (const float*)d_in[9];
    const float* fc1_w  = (const float*)d_in[10];
    const float* fc1_b  = (const float*)d_in[11];
    const float* fc2_w  = (const float*)d_in[12];
    const float* fc2_b  = (const float*)d_in[13];
    float* out = (float*)d_out;

    char* ws = (char*)d_ws;
    float2* stats1 = (float2*)ws;                     // 802816 B
    float2* stats2 = (float2*)(ws + 802816);          // 802816 B
    float*  x2     = (float*)(ws + 1605632);          // 77070336 B

    ln_stats_kernel<<<TTOK / 4, 256, 0, stream>>>(x, stats1);
    attn_kernel<<<32 * 64, 256, 0, stream>>>(x, stats1, g1, b1, qkv_w, qkv_b,
                                             rpb, proj_w, proj_b, x2);
    ln_stats_kernel<<<TTOK / 4, 256, 0, stream>>>(x2, stats2);
    mlp_kernel<<<TTOK / 64, 256, 0, stream>>>(x2, stats2, g2, b2,
                                              fc1_w, fc1_b, fc2_w, fc2_b, out);
}

// Round 2
// 3067.099 us; speedup vs baseline: 3.1711x; 3.1711x over previous
//
#include <hip/hip_runtime.h>
#include <hip/hip_bf16.h>

#define CDIM 192
#define WSZ 7
#define SSZ 3
#define NHEAD 6
#define HD 32
#define NTOK 49          // tokens per window
#define HW 56
#define TTOK (32*56*56)  // 100352 tokens total

typedef __attribute__((ext_vector_type(8))) short bf16x8;
typedef __attribute__((ext_vector_type(4))) float f32x4;

__device__ inline ushort f2bf(float v) {
    union { float f; unsigned u; } x; x.f = v;
    unsigned r = x.u + 0x7fff + ((x.u >> 16) & 1);
    return (ushort)(r >> 16);
}

__device__ inline float gelu_f(float x) {
    // tanh-form GELU; |deviation from exact erf form| < ~1e-3, far under threshold
    float t = 0.7978845608028654f * x * (1.0f + 0.044715f * x * x);
    float e = __expf(-2.0f * t);
    return 0.5f * x * (1.0f + (1.0f - e) / (1.0f + e));
}

// ---------------------------------------------------------------------------
// LayerNorm stats: one wave per token, 4 tokens per 256-thread block.
// ---------------------------------------------------------------------------
__global__ __launch_bounds__(256) void ln_stats_kernel(const float* __restrict__ x,
                                                       float2* __restrict__ stats) {
    int wid  = threadIdx.x >> 6;
    int lane = threadIdx.x & 63;
    int token = blockIdx.x * 4 + wid;
    const float* p = x + (size_t)token * CDIM;
    float a0 = p[lane], a1 = p[lane + 64], a2 = p[lane + 128];
    float s = a0 + a1 + a2;
    float q = a0 * a0 + a1 * a1 + a2 * a2;
    #pragma unroll
    for (int m = 32; m >= 1; m >>= 1) {
        s += __shfl_xor(s, m);
        q += __shfl_xor(q, m);
    }
    if (lane == 0) {
        float mean = s * (1.0f / 192.0f);
        float var  = q * (1.0f / 192.0f) - mean * mean;
        stats[token] = make_float2(mean, rsqrtf(var + 1e-5f));
    }
}

// ---------------------------------------------------------------------------
// Weight prep: bf16 N-major transposes so MFMA B-fragments are contiguous.
// W1T[n][k] = fc1_w[k][n]  (768 x 192),  W2T[c][k] = fc2_w[k][c]  (192 x 768)
// ---------------------------------------------------------------------------
__global__ __launch_bounds__(256) void prep_weights_kernel(
    const float* __restrict__ fc1_w, const float* __restrict__ fc2_w,
    ushort* __restrict__ W1T, ushort* __restrict__ W2T) {
    int idx = blockIdx.x * 256 + threadIdx.x;  // grid covers exactly 147456
    {
        int n = idx / 192, k = idx - n * 192;
        W1T[idx] = f2bf(fc1_w[k * 768 + n]);
    }
    {
        int c = idx / 768, k = idx - c * 768;
        W2T[idx] = f2bf(fc2_w[k * 192 + c]);
    }
}

// ---------------------------------------------------------------------------
// Fused shifted-window attention + proj + residual (unchanged from round 0).
// ---------------------------------------------------------------------------
__global__ __launch_bounds__(256) void attn_kernel(
    const float*  __restrict__ x,
    const float2* __restrict__ stats,
    const float*  __restrict__ g1, const float* __restrict__ b1,
    const float*  __restrict__ qkv_w, const float* __restrict__ qkv_b,
    const float*  __restrict__ rpb,
    const float*  __restrict__ proj_w, const float* __restrict__ proj_b,
    float* __restrict__ x2)
{
    __shared__ __hip_bfloat16 xw[NTOK * CDIM];
    __shared__ float qs[NTOK * 33];
    __shared__ float ks[NTOK * 33];
    __shared__ float vs[NTOK * 33];
    __shared__ float sc[NTOK * NTOK];
    __shared__ float ho[NTOK * 33];

    const int bid = blockIdx.x;
    const int b   = bid >> 6;
    const int w   = bid & 63;
    const int wh  = w >> 3, ww = w & 7;
    const int tid = threadIdx.x;

    for (int e = tid; e < NTOK * CDIM; e += 256) {
        int n = e / CDIM, c = e - n * CDIM;
        int i = n / 7, j = n - i * 7;
        int hs = wh * 7 + i + SSZ; if (hs >= HW) hs -= HW;
        int ws = ww * 7 + j + SSZ; if (ws >= HW) ws -= HW;
        int tok = (b * HW + hs) * HW + ws;
        float2 st = stats[tok];
        float v = x[(size_t)tok * CDIM + c];
        xw[n * CDIM + c] = __float2bfloat16((v - st.x) * st.y * g1[c] + b1[c]);
    }
    __syncthreads();

    float acc[48];
    #pragma unroll
    for (int j = 0; j < 48; j++) acc[j] = 0.0f;
    const int pn  = tid >> 2;
    const int pc0 = (tid & 3) * 48;

    const float scale = 0.17677669529663687f;

    for (int h = 0; h < NHEAD; h++) {
        for (int e = tid; e < NTOK * HD; e += 256) {
            int n = e >> 5, d = e & 31;
            int cq = h * 32 + d;
            float aq = qkv_b[cq], ak = qkv_b[192 + cq], av = qkv_b[384 + cq];
            const float* wq = qkv_w + cq;
            for (int c = 0; c < CDIM; c++) {
                float xv = __bfloat162float(xw[n * CDIM + c]);
                const float* wr = wq + c * 576;
                aq += xv * wr[0];
                ak += xv * wr[192];
                av += xv * wr[384];
            }
            qs[n * 33 + d] = aq * scale;
            ks[n * 33 + d] = ak;
            vs[n * 33 + d] = av;
        }
        __syncthreads();

        for (int e = tid; e < NTOK * NTOK; e += 256) {
            int i = e / 49, j = e - i * 49;
            float a = 0.0f;
            #pragma unroll 8
            for (int d = 0; d < 32; d++) a += qs[i * 33 + d] * ks[j * 33 + d];
            int ih = i / 7, iw = i - ih * 7;
            int jh = j / 7, jw = j - jh * 7;
            a += rpb[((ih - jh + 6) * 13 + (iw - jw + 6)) * NHEAD + h];
            int pi = wh * 7 + ih, qi = ww * 7 + iw;
            int pj = wh * 7 + jh, qj = ww * 7 + jw;
            int ci = (pi < 49 ? 0 : (pi < 53 ? 1 : 2)) * 3 + (qi < 49 ? 0 : (qi < 53 ? 1 : 2));
            int cj = (pj < 49 ? 0 : (pj < 53 ? 1 : 2)) * 3 + (qj < 49 ? 0 : (qj < 53 ? 1 : 2));
            if (ci != cj) a -= 100.0f;
            sc[i * 49 + j] = a;
        }
        __syncthreads();

        if (tid < NTOK) {
            float m = -1e30f;
            for (int j = 0; j < 49; j++) m = fmaxf(m, sc[tid * 49 + j]);
            float s = 0.0f;
            for (int j = 0; j < 49; j++) {
                float e = __expf(sc[tid * 49 + j] - m);
                sc[tid * 49 + j] = e;
                s += e;
            }
            float inv = 1.0f / s;
            for (int j = 0; j < 49; j++) sc[tid * 49 + j] *= inv;
        }
        __syncthreads();

        for (int e = tid; e < NTOK * HD; e += 256) {
            int n = e >> 5, d = e & 31;
            float a = 0.0f;
            for (int j = 0; j < 49; j++) a += sc[n * 49 + j] * vs[j * 33 + d];
            ho[n * 33 + d] = a;
        }
        __syncthreads();

        if (tid < 196) {
            const float* wp = proj_w + (size_t)h * 32 * 192 + pc0;
            for (int d = 0; d < 32; d++) {
                float hv = ho[pn * 33 + d];
                const float4* w4 = (const float4*)(wp + (size_t)d * 192);
                #pragma unroll
                for (int j4 = 0; j4 < 12; j4++) {
                    float4 wv = w4[j4];
                    acc[j4 * 4 + 0] += hv * wv.x;
                    acc[j4 * 4 + 1] += hv * wv.y;
                    acc[j4 * 4 + 2] += hv * wv.z;
                    acc[j4 * 4 + 3] += hv * wv.w;
                }
            }
        }
        __syncthreads();
    }

    if (tid < 196) {
        int i = pn / 7, j = pn - i * 7;
        int hs = wh * 7 + i + SSZ; if (hs >= HW) hs -= HW;
        int ws = ww * 7 + j + SSZ; if (ws >= HW) ws -= HW;
        size_t tok = ((size_t)b * HW + hs) * HW + ws;
        const float4* xr = (const float4*)(x + tok * CDIM + pc0);
        const float4* pb = (const float4*)(proj_b + pc0);
        float4* o = (float4*)(x2 + tok * CDIM + pc0);
        #pragma unroll
        for (int j4 = 0; j4 < 12; j4++) {
            float4 xv = xr[j4], bv = pb[j4], ov;
            ov.x = xv.x + bv.x + acc[j4 * 4 + 0];
            ov.y = xv.y + bv.y + acc[j4 * 4 + 1];
            ov.z = xv.z + bv.z + acc[j4 * 4 + 2];
            ov.w = xv.w + bv.w + acc[j4 * 4 + 3];
            o[j4] = ov;
        }
    }
}

// ---------------------------------------------------------------------------
// MFMA MLP: out = x2 + fc2(gelu(fc1(LN2(x2)))).
// 64 tokens/block, 4 waves; hidden chunked by 128; 16x16x32 bf16 MFMA.
// A (LN'd tokens) staged bf16 in LDS (pitch 200: bank-balanced b128 reads).
// B fragments read straight from L2-resident bf16 transposed weights.
// ---------------------------------------------------------------------------
__global__ __launch_bounds__(256) void mlp_mfma_kernel(
    const float*  __restrict__ x2,
    const float2* __restrict__ stats,
    const float*  __restrict__ g2, const float* __restrict__ b2,
    const ushort* __restrict__ W1T, const float* __restrict__ fc1_b,
    const ushort* __restrict__ W2T, const float* __restrict__ fc2_b,
    float* __restrict__ out)
{
    __shared__ ushort A[64 * 200];    // 25600 B
    __shared__ ushort Hs[64 * 136];   // 17408 B

    const int tid = threadIdx.x;
    const int l   = tid & 63;
    const int wid = tid >> 6;
    const size_t tok0 = (size_t)blockIdx.x * 64;

    // ---- stage LN2(x2) tile as bf16 ----
    {
        int n  = tid >> 2;
        int c0 = (tid & 3) * 48;
        size_t tok = tok0 + n;
        float2 st = stats[tok];
        const float4* xr = (const float4*)(x2 + tok * CDIM + c0);
        const float4* gg = (const float4*)(g2 + c0);
        const float4* bb = (const float4*)(b2 + c0);
        #pragma unroll
        for (int j4 = 0; j4 < 12; j4++) {
            float4 v = xr[j4], g = gg[j4], b = bb[j4];
            int c = n * 200 + c0 + j4 * 4;
            A[c + 0] = f2bf((v.x - st.x) * st.y * g.x + b.x);
            A[c + 1] = f2bf((v.y - st.x) * st.y * g.y + b.y);
            A[c + 2] = f2bf((v.z - st.x) * st.y * g.z + b.z);
            A[c + 3] = f2bf((v.w - st.x) * st.y * g.w + b.w);
        }
    }
    __syncthreads();

    const int lrow = l & 15;          // fragment row/col index
    const int kg   = (l >> 4) * 8;    // k sub-offset within fragment
    const int arow = wid * 16 + lrow; // this wave's M-band row for A-frags

    // GEMM1 A-fragments: loaded once, reused for all 6 hidden chunks
    bf16x8 a1[6];
    #pragma unroll
    for (int ks = 0; ks < 6; ks++)
        a1[ks] = *(const bf16x8*)&A[arow * 200 + ks * 32 + kg];

    f32x4 acc2[12];
    #pragma unroll
    for (int i = 0; i < 12; i++) acc2[i] = (f32x4){0.f, 0.f, 0.f, 0.f};

    for (int ch = 0; ch < 6; ch++) {
        const int n0 = ch * 128;
        if (ch) __syncthreads();  // prior GEMM2 reads of Hs complete

        // ---- GEMM1: H[64 x 128] = gelu(A @ W1[:, n0:n0+128] + b1) ----
        #pragma unroll
        for (int nt = 0; nt < 8; nt++) {
            f32x4 a = (f32x4){0.f, 0.f, 0.f, 0.f};
            const ushort* bp = W1T + (size_t)(n0 + nt * 16 + lrow) * 192 + kg;
            #pragma unroll
            for (int ks = 0; ks < 6; ks++) {
                bf16x8 bfr = *(const bf16x8*)(bp + ks * 32);
                a = __builtin_amdgcn_mfma_f32_16x16x32_bf16(a1[ks], bfr, a, 0, 0, 0);
            }
            float bias = fc1_b[n0 + nt * 16 + lrow];
            int hrow = wid * 16 + ((l >> 4) << 2);
            int hcol = nt * 16 + lrow;
            #pragma unroll
            for (int j = 0; j < 4; j++) {
                float v = a[j] + bias;
                Hs[(hrow + j) * 136 + hcol] = f2bf(gelu_f(v));
            }
        }
        __syncthreads();

        // ---- GEMM2: acc2 += H @ W2[n0:n0+128, :] ----
        bf16x8 a2[4];
        #pragma unroll
        for (int ks = 0; ks < 4; ks++)
            a2[ks] = *(const bf16x8*)&Hs[arow * 136 + ks * 32 + kg];
        #pragma unroll
        for (int nt = 0; nt < 12; nt++) {
            const ushort* bp = W2T + (size_t)(nt * 16 + lrow) * 768 + n0 + kg;
            #pragma unroll
            for (int ks = 0; ks < 4; ks++) {
                bf16x8 bfr = *(const bf16x8*)(bp + ks * 32);
                acc2[nt] = __builtin_amdgcn_mfma_f32_16x16x32_bf16(a2[ks], bfr, acc2[nt], 0, 0, 0);
            }
        }
    }

    // ---- epilogue: out = x2 + acc2 + fc2_b ----
    const int orow = wid * 16 + ((l >> 4) << 2);
    #pragma unroll
    for (int nt = 0; nt < 12; nt++) {
        int c = nt * 16 + lrow;
        float fb = fc2_b[c];
        #pragma unroll
        for (int j = 0; j < 4; j++) {
            size_t tok = tok0 + orow + j;
            out[tok * CDIM + c] = x2[tok * CDIM + c] + acc2[nt][j] + fb;
        }
    }
}

// ---------------------------------------------------------------------------
extern "C" void kernel_launch(void* const* d_in, const int* in_sizes, int n_in,
                              void* d_out, int out_size, void* d_ws, size_t ws_size,
                              hipStream_t stream) {
    const float* x      = (const float*)d_in[0];
    const float* g1     = (const float*)d_in[1];
    const float* b1     = (const float*)d_in[2];
    const float* qkv_w  = (const float*)d_in[3];
    const float* qkv_b  = (const float*)d_in[4];
    const float* rpb    = (const float*)d_in[5];
    const float* proj_w = (const float*)d_in[6];
    const float* proj_b = (const float*)d_in[7];
    const float* g2     = (const float*)d_in[8];
    const float* b2     = (const float*)d_in[9];
    const float* fc1_w  = (const float*)d_in[10];
    const float* fc1_b  = (const float*)d_in[11];
    const float* fc2_w  = (const float*)d_in[12];
    const float* fc2_b  = (const float*)d_in[13];
    float* out = (float*)d_out;

    char* ws = (char*)d_ws;
    float2* stats1 = (float2*)ws;                     // 802816 B
    float2* stats2 = (float2*)(ws + 802816);          // 802816 B
    float*  x2     = (float*)(ws + 1605632);          // 77070336 B
    ushort* W1T    = (ushort*)(ws + 78675968);        // 294912 B
    ushort* W2T    = (ushort*)(ws + 78970880);        // 294912 B

    ln_stats_kernel<<<TTOK / 4, 256, 0, stream>>>(x, stats1);
    prep_weights_kernel<<<576, 256, 0, stream>>>(fc1_w, fc2_w, W1T, W2T);
    attn_kernel<<<32 * 64, 256, 0, stream>>>(x, stats1, g1, b1, qkv_w, qkv_b,
                                             rpb, proj_w, proj_b, x2);
    ln_stats_kernel<<<TTOK / 4, 256, 0, stream>>>(x2, stats2);
    mlp_mfma_kernel<<<TTOK / 64, 256, 0, stream>>>(x2, stats2, g2, b2,
                                                   W1T, fc1_b, W2T, fc2_b, out);
}

// Round 3
// 926.141 us; speedup vs baseline: 10.5017x; 3.3117x over previous
//
#include <hip/hip_runtime.h>
#include <hip/hip_bf16.h>

#define CDIM 192
#define WSZ 7
#define SSZ 3
#define NHEAD 6
#define HD 32
#define NTOK 49          // tokens per window
#define HW 56
#define TTOK (32*56*56)  // 100352 tokens total

typedef __attribute__((ext_vector_type(8))) short bf16x8;
typedef __attribute__((ext_vector_type(4))) float f32x4;

__device__ inline ushort f2bf(float v) {
    union { float f; unsigned u; } x; x.f = v;
    unsigned r = x.u + 0x7fff + ((x.u >> 16) & 1);
    return (ushort)(r >> 16);
}

__device__ inline float gelu_f(float x) {
    float t = 0.7978845608028654f * x * (1.0f + 0.044715f * x * x);
    float e = __expf(-2.0f * t);
    return 0.5f * x * (1.0f + (1.0f - e) / (1.0f + e));
}

// ---------------------------------------------------------------------------
// LayerNorm stats: one wave per token, 4 tokens per 256-thread block.
// ---------------------------------------------------------------------------
__global__ __launch_bounds__(256) void ln_stats_kernel(const float* __restrict__ x,
                                                       float2* __restrict__ stats) {
    int wid  = threadIdx.x >> 6;
    int lane = threadIdx.x & 63;
    int token = blockIdx.x * 4 + wid;
    const float* p = x + (size_t)token * CDIM;
    float a0 = p[lane], a1 = p[lane + 64], a2 = p[lane + 128];
    float s = a0 + a1 + a2;
    float q = a0 * a0 + a1 * a1 + a2 * a2;
    #pragma unroll
    for (int m = 32; m >= 1; m >>= 1) {
        s += __shfl_xor(s, m);
        q += __shfl_xor(q, m);
    }
    if (lane == 0) {
        float mean = s * (1.0f / 192.0f);
        float var  = q * (1.0f / 192.0f) - mean * mean;
        stats[token] = make_float2(mean, rsqrtf(var + 1e-5f));
    }
}

// ---------------------------------------------------------------------------
// Weight prep: bf16 N-major transposes for all GEMM B-operands.
// W1T[768][192], W2T[192][768], WqkvT[576][192], PjT[192][192]
// ---------------------------------------------------------------------------
__global__ __launch_bounds__(256) void prep_weights_kernel(
    const float* __restrict__ fc1_w, const float* __restrict__ fc2_w,
    const float* __restrict__ qkv_w, const float* __restrict__ proj_w,
    ushort* __restrict__ W1T, ushort* __restrict__ W2T,
    ushort* __restrict__ WqkvT, ushort* __restrict__ PjT) {
    int idx = blockIdx.x * 256 + threadIdx.x;  // grid covers exactly 147456
    {
        int n = idx / 192, k = idx - n * 192;
        W1T[idx] = f2bf(fc1_w[k * 768 + n]);
    }
    {
        int c = idx / 768, k = idx - c * 768;
        W2T[idx] = f2bf(fc2_w[k * 192 + c]);
    }
    if (idx < 576 * 192) {
        int n = idx / 192, k = idx - n * 192;
        WqkvT[idx] = f2bf(qkv_w[k * 576 + n]);
    }
    if (idx < 192 * 192) {
        int n = idx / 192, k = idx - n * 192;
        PjT[idx] = f2bf(proj_w[k * 192 + n]);
    }
}

// ---------------------------------------------------------------------------
// MFMA shifted-window attention + proj + residual.
// One block (4 waves) per window; wave w owns token rows w*16..w*16+15
// of the 49->64 padded window. x2 = x + proj(attn(LN1(x))) at same pos.
// ---------------------------------------------------------------------------
__global__ __launch_bounds__(256) void attn_mfma_kernel(
    const float*  __restrict__ x,
    const float2* __restrict__ stats,
    const float*  __restrict__ g1, const float* __restrict__ b1,
    const ushort* __restrict__ WqkvT, const float* __restrict__ qkv_b,
    const float*  __restrict__ rpb,
    const ushort* __restrict__ PjT, const float* __restrict__ proj_b,
    float* __restrict__ x2)
{
    __shared__ ushort A[64 * 200];    // 25600 B  LN'd tokens (rows 49-63 zero)
    __shared__ ushort Qs[64 * 40];    //  5120 B  q (scaled), [tok][dim]
    __shared__ ushort Ks[64 * 40];    //  5120 B  k, [tok][dim]
    __shared__ ushort Vs[32 * 72];    //  4608 B  v, [dim][tok]
    __shared__ ushort Ps[64 * 72];    //  9216 B  softmax(P), [tok_i][tok_j]
    __shared__ ushort Ho[64 * 40];    //  5120 B  head out, [tok][dim]
    __shared__ float  rpbl[169 * 6];  //  4056 B
    __shared__ float  qbl[576];       //  2304 B   -> total 61144 B, 2 blk/CU

    const int bid = blockIdx.x;
    const int b   = bid >> 6;
    const int w   = bid & 63;
    const int wh  = w >> 3, ww = w & 7;
    const int tid = threadIdx.x;
    const int l   = tid & 63;
    const int wid = tid >> 6;

    for (int e = tid; e < 169 * 6; e += 256) rpbl[e] = rpb[e];
    if (tid < 576 - 256) qbl[512 + tid] = qkv_b[512 + tid];
    qbl[tid] = qkv_b[tid];
    qbl[256 + tid] = qkv_b[256 + tid];

    // ---- stage A = LN1(x window, shifted), bf16; pad rows zero ----
    {
        int n  = tid >> 2;
        int c0 = (tid & 3) * 48;
        if (n < NTOK) {
            int i = n / 7, j = n - i * 7;
            int hs = wh * 7 + i + SSZ; if (hs >= HW) hs -= HW;
            int ws = ww * 7 + j + SSZ; if (ws >= HW) ws -= HW;
            size_t tok = ((size_t)b * HW + hs) * HW + ws;
            float2 st = stats[tok];
            const float4* xr = (const float4*)(x + tok * CDIM + c0);
            const float4* gg = (const float4*)(g1 + c0);
            const float4* bb = (const float4*)(b1 + c0);
            #pragma unroll
            for (int j4 = 0; j4 < 12; j4++) {
                float4 v = xr[j4], g = gg[j4], bv = bb[j4];
                int c = n * 200 + c0 + j4 * 4;
                A[c + 0] = f2bf((v.x - st.x) * st.y * g.x + bv.x);
                A[c + 1] = f2bf((v.y - st.x) * st.y * g.y + bv.y);
                A[c + 2] = f2bf((v.z - st.x) * st.y * g.z + bv.z);
                A[c + 3] = f2bf((v.w - st.x) * st.y * g.w + bv.w);
            }
        } else {
            #pragma unroll
            for (int j4 = 0; j4 < 12; j4++) {
                int c = n * 200 + c0 + j4 * 4;
                A[c + 0] = 0; A[c + 1] = 0; A[c + 2] = 0; A[c + 3] = 0;
            }
        }
    }
    __syncthreads();

    const int lrow = l & 15;
    const int rg   = l >> 4;
    const int kg   = rg * 8;
    const int m0   = wid * 16;
    const int arow = m0 + lrow;
    const float scale = 0.17677669529663687f;

    // A-fragments: one per K-step, reused across all 6 heads
    bf16x8 a1[6];
    #pragma unroll
    for (int ks = 0; ks < 6; ks++)
        a1[ks] = *(const bf16x8*)&A[arow * 200 + ks * 32 + kg];

    // per-lane bias/mask tables (head-independent): acc elem (nt, jj) is
    // score[i = m0+rg*4+jj][j = nt*16+lrow]
    int   rpi16[4][4];
    float madd[4][4];
    #pragma unroll
    for (int jj = 0; jj < 4; jj++) {
        int i  = m0 + rg * 4 + jj;
        int ih = (i * 9363) >> 16, iw = i - ih * 7;
        int pi = wh * 7 + ih, qi = ww * 7 + iw;
        int ci = (pi < 49 ? 0 : (pi < 53 ? 1 : 2)) * 3 + (qi < 49 ? 0 : (qi < 53 ? 1 : 2));
        #pragma unroll
        for (int nt = 0; nt < 4; nt++) {
            int j  = nt * 16 + lrow;
            int jh = (j * 9363) >> 16, jw = j - jh * 7;
            int pj = wh * 7 + jh, qj = ww * 7 + jw;
            int cj = (pj < 49 ? 0 : (pj < 53 ? 1 : 2)) * 3 + (qj < 49 ? 0 : (qj < 53 ? 1 : 2));
            int rpi = (ih - jh + 6) * 13 + (iw - jw + 6);
            rpi = rpi < 0 ? 0 : (rpi > 168 ? 168 : rpi);
            rpi16[jj][nt] = rpi * 6;
            madd[jj][nt] = (j >= NTOK) ? -1e30f : ((ci != cj) ? -100.0f : 0.0f);
        }
    }

    f32x4 acc2[12];
    #pragma unroll
    for (int i = 0; i < 12; i++) acc2[i] = (f32x4){0.f, 0.f, 0.f, 0.f};

    for (int h = 0; h < NHEAD; h++) {
        __syncthreads();  // prior head's Ks/Vs consumers done

        // ---- QKV GEMM for head h: tiles q0,q1,k0,k1,v0,v1 ----
        #pragma unroll
        for (int t = 0; t < 6; t++) {
            const int nglob = (t >> 1) * 192 + h * 32 + (t & 1) * 16;
            f32x4 a = (f32x4){0.f, 0.f, 0.f, 0.f};
            const ushort* bp = WqkvT + (size_t)(nglob + lrow) * 192 + kg;
            #pragma unroll
            for (int ks = 0; ks < 6; ks++) {
                bf16x8 bfr = *(const bf16x8*)(bp + ks * 32 * sizeof(ushort) / 2);
                a = __builtin_amdgcn_mfma_f32_16x16x32_bf16(a1[ks], bfr, a, 0, 0, 0);
            }
            float bias = qbl[nglob + lrow];
            const int dl = (t & 1) * 16 + lrow;  // dim-local 0..31
            if (t < 2) {
                #pragma unroll
                for (int jj = 0; jj < 4; jj++)
                    Qs[(m0 + rg * 4 + jj) * 40 + dl] = f2bf((a[jj] + bias) * scale);
            } else if (t < 4) {
                #pragma unroll
                for (int jj = 0; jj < 4; jj++)
                    Ks[(m0 + rg * 4 + jj) * 40 + dl] = f2bf(a[jj] + bias);
            } else {
                #pragma unroll
                for (int jj = 0; jj < 4; jj++)
                    Vs[dl * 72 + m0 + rg * 4 + jj] = f2bf(a[jj] + bias);
            }
        }
        __syncthreads();  // K/V staged (cross-wave)

        // ---- scores + bias, in-register ----
        bf16x8 aq = *(const bf16x8*)&Qs[arow * 40 + kg];
        f32x4 s4[4];
        #pragma unroll
        for (int nt = 0; nt < 4; nt++) {
            bf16x8 bk = *(const bf16x8*)&Ks[(nt * 16 + lrow) * 40 + kg];
            f32x4 a = (f32x4){0.f, 0.f, 0.f, 0.f};
            a = __builtin_amdgcn_mfma_f32_16x16x32_bf16(aq, bk, a, 0, 0, 0);
            #pragma unroll
            for (int jj = 0; jj < 4; jj++)
                s4[nt][jj] = a[jj] + rpbl[rpi16[jj][nt] + h] + madd[jj][nt];
        }

        // ---- in-register softmax: row spread over 16-lane group x 4 tiles ----
        #pragma unroll
        for (int jj = 0; jj < 4; jj++) {
            float m = fmaxf(fmaxf(s4[0][jj], s4[1][jj]), fmaxf(s4[2][jj], s4[3][jj]));
            #pragma unroll
            for (int msk = 1; msk < 16; msk <<= 1) m = fmaxf(m, __shfl_xor(m, msk));
            float e0 = __expf(s4[0][jj] - m);
            float e1 = __expf(s4[1][jj] - m);
            float e2 = __expf(s4[2][jj] - m);
            float e3 = __expf(s4[3][jj] - m);
            float r = e0 + e1 + e2 + e3;
            #pragma unroll
            for (int msk = 1; msk < 16; msk <<= 1) r += __shfl_xor(r, msk);
            float inv = 1.0f / r;
            int prow = (m0 + rg * 4 + jj) * 72;
            Ps[prow +  0 + lrow] = f2bf(e0 * inv);
            Ps[prow + 16 + lrow] = f2bf(e1 * inv);
            Ps[prow + 32 + lrow] = f2bf(e2 * inv);
            Ps[prow + 48 + lrow] = f2bf(e3 * inv);
        }

        // ---- PV: head_out[64x32] = P @ V  (wave-local rows) ----
        #pragma unroll
        for (int nt = 0; nt < 2; nt++) {
            f32x4 a = (f32x4){0.f, 0.f, 0.f, 0.f};
            #pragma unroll
            for (int ks = 0; ks < 2; ks++) {
                bf16x8 pa = *(const bf16x8*)&Ps[arow * 72 + ks * 32 + kg];
                bf16x8 bv = *(const bf16x8*)&Vs[(nt * 16 + lrow) * 72 + ks * 32 + kg];
                a = __builtin_amdgcn_mfma_f32_16x16x32_bf16(pa, bv, a, 0, 0, 0);
            }
            #pragma unroll
            for (int jj = 0; jj < 4; jj++)
                Ho[(m0 + rg * 4 + jj) * 40 + nt * 16 + lrow] = f2bf(a[jj]);
        }

        // ---- proj partial: acc2 += head_out @ proj_w[h*32:(h+1)*32, :] ----
        bf16x8 ah = *(const bf16x8*)&Ho[arow * 40 + kg];
        #pragma unroll
        for (int nt = 0; nt < 12; nt++) {
            bf16x8 bp2 = *(const bf16x8*)&PjT[(size_t)(nt * 16 + lrow) * 192 + h * 32 + kg];
            acc2[nt] = __builtin_amdgcn_mfma_f32_16x16x32_bf16(ah, bp2, acc2[nt], 0, 0, 0);
        }
    }

    // ---- epilogue: x2 = x + proj_out + proj_b (49 real rows only) ----
    size_t gbase[4];
    int    valid[4];
    #pragma unroll
    for (int jj = 0; jj < 4; jj++) {
        int n = m0 + rg * 4 + jj;
        valid[jj] = (n < NTOK);
        int i = (n * 9363) >> 16, j = n - i * 7;
        int hs = wh * 7 + i + SSZ; if (hs >= HW) hs -= HW;
        int ws = ww * 7 + j + SSZ; if (ws >= HW) ws -= HW;
        gbase[jj] = (((size_t)b * HW + hs) * HW + ws) * CDIM;
    }
    #pragma unroll
    for (int nt = 0; nt < 12; nt++) {
        int c = nt * 16 + lrow;
        float pb = proj_b[c];
        #pragma unroll
        for (int jj = 0; jj < 4; jj++) {
            if (valid[jj])
                x2[gbase[jj] + c] = x[gbase[jj] + c] + pb + acc2[nt][jj];
        }
    }
}

// ---------------------------------------------------------------------------
// MFMA MLP (unchanged from round 1).
// ---------------------------------------------------------------------------
__global__ __launch_bounds__(256) void mlp_mfma_kernel(
    const float*  __restrict__ x2,
    const float2* __restrict__ stats,
    const float*  __restrict__ g2, const float* __restrict__ b2,
    const ushort* __restrict__ W1T, const float* __restrict__ fc1_b,
    const ushort* __restrict__ W2T, const float* __restrict__ fc2_b,
    float* __restrict__ out)
{
    __shared__ ushort A[64 * 200];
    __shared__ ushort Hs[64 * 136];

    const int tid = threadIdx.x;
    const int l   = tid & 63;
    const int wid = tid >> 6;
    const size_t tok0 = (size_t)blockIdx.x * 64;

    {
        int n  = tid >> 2;
        int c0 = (tid & 3) * 48;
        size_t tok = tok0 + n;
        float2 st = stats[tok];
        const float4* xr = (const float4*)(x2 + tok * CDIM + c0);
        const float4* gg = (const float4*)(g2 + c0);
        const float4* bb = (const float4*)(b2 + c0);
        #pragma unroll
        for (int j4 = 0; j4 < 12; j4++) {
            float4 v = xr[j4], g = gg[j4], b = bb[j4];
            int c = n * 200 + c0 + j4 * 4;
            A[c + 0] = f2bf((v.x - st.x) * st.y * g.x + b.x);
            A[c + 1] = f2bf((v.y - st.x) * st.y * g.y + b.y);
            A[c + 2] = f2bf((v.z - st.x) * st.y * g.z + b.z);
            A[c + 3] = f2bf((v.w - st.x) * st.y * g.w + b.w);
        }
    }
    __syncthreads();

    const int lrow = l & 15;
    const int kg   = (l >> 4) * 8;
    const int arow = wid * 16 + lrow;

    bf16x8 a1[6];
    #pragma unroll
    for (int ks = 0; ks < 6; ks++)
        a1[ks] = *(const bf16x8*)&A[arow * 200 + ks * 32 + kg];

    f32x4 acc2[12];
    #pragma unroll
    for (int i = 0; i < 12; i++) acc2[i] = (f32x4){0.f, 0.f, 0.f, 0.f};

    for (int ch = 0; ch < 6; ch++) {
        const int n0 = ch * 128;
        if (ch) __syncthreads();

        #pragma unroll
        for (int nt = 0; nt < 8; nt++) {
            f32x4 a = (f32x4){0.f, 0.f, 0.f, 0.f};
            const ushort* bp = W1T + (size_t)(n0 + nt * 16 + lrow) * 192 + kg;
            #pragma unroll
            for (int ks = 0; ks < 6; ks++) {
                bf16x8 bfr = *(const bf16x8*)(bp + ks * 32);
                a = __builtin_amdgcn_mfma_f32_16x16x32_bf16(a1[ks], bfr, a, 0, 0, 0);
            }
            float bias = fc1_b[n0 + nt * 16 + lrow];
            int hrow = wid * 16 + ((l >> 4) << 2);
            int hcol = nt * 16 + lrow;
            #pragma unroll
            for (int j = 0; j < 4; j++) {
                float v = a[j] + bias;
                Hs[(hrow + j) * 136 + hcol] = f2bf(gelu_f(v));
            }
        }
        __syncthreads();

        bf16x8 a2[4];
        #pragma unroll
        for (int ks = 0; ks < 4; ks++)
            a2[ks] = *(const bf16x8*)&Hs[arow * 136 + ks * 32 + kg];
        #pragma unroll
        for (int nt = 0; nt < 12; nt++) {
            const ushort* bp = W2T + (size_t)(nt * 16 + lrow) * 768 + n0 + kg;
            #pragma unroll
            for (int ks = 0; ks < 4; ks++) {
                bf16x8 bfr = *(const bf16x8*)(bp + ks * 32);
                acc2[nt] = __builtin_amdgcn_mfma_f32_16x16x32_bf16(a2[ks], bfr, acc2[nt], 0, 0, 0);
            }
        }
    }

    const int orow = wid * 16 + ((l >> 4) << 2);
    #pragma unroll
    for (int nt = 0; nt < 12; nt++) {
        int c = nt * 16 + lrow;
        float fb = fc2_b[c];
        #pragma unroll
        for (int j = 0; j < 4; j++) {
            size_t tok = tok0 + orow + j;
            out[tok * CDIM + c] = x2[tok * CDIM + c] + acc2[nt][j] + fb;
        }
    }
}

// ---------------------------------------------------------------------------
extern "C" void kernel_launch(void* const* d_in, const int* in_sizes, int n_in,
                              void* d_out, int out_size, void* d_ws, size_t ws_size,
                              hipStream_t stream) {
    const float* x      = (const float*)d_in[0];
    const float* g1     = (const float*)d_in[1];
    const float* b1     = (const float*)d_in[2];
    const float* qkv_w  = (const float*)d_in[3];
    const float* qkv_b  = (const float*)d_in[4];
    const float* rpb    = (const float*)d_in[5];
    const float* proj_w = (const float*)d_in[6];
    const float* proj_b = (const float*)d_in[7];
    const float* g2     = (const float*)d_in[8];
    const float* b2     = (const float*)d_in[9];
    const float* fc1_w  = (const float*)d_in[10];
    const float* fc1_b  = (const float*)d_in[11];
    const float* fc2_w  = (const float*)d_in[12];
    const float* fc2_b  = (const float*)d_in[13];
    float* out = (float*)d_out;

    char* ws = (char*)d_ws;
    float2* stats1 = (float2*)ws;                     //   802816 B
    float2* stats2 = (float2*)(ws + 802816);          //   802816 B
    float*  x2     = (float*)(ws + 1605632);          // 77070336 B
    ushort* W1T    = (ushort*)(ws + 78675968);        //   294912 B
    ushort* W2T    = (ushort*)(ws + 78970880);        //   294912 B
    ushort* WqkvT  = (ushort*)(ws + 79265792);        //   221184 B
    ushort* PjT    = (ushort*)(ws + 79486976);        //    73728 B

    ln_stats_kernel<<<TTOK / 4, 256, 0, stream>>>(x, stats1);
    prep_weights_kernel<<<576, 256, 0, stream>>>(fc1_w, fc2_w, qkv_w, proj_w,
                                                 W1T, W2T, WqkvT, PjT);
    attn_mfma_kernel<<<32 * 64, 256, 0, stream>>>(x, stats1, g1, b1,
                                                  WqkvT, qkv_b, rpb,
                                                  PjT, proj_b, x2);
    ln_stats_kernel<<<TTOK / 4, 256, 0, stream>>>(x2, stats2);
    mlp_mfma_kernel<<<TTOK / 64, 256, 0, stream>>>(x2, stats2, g2, b2,
                                                   W1T, fc1_b, W2T, fc2_b, out);
}

// Round 4
// 611.637 us; speedup vs baseline: 15.9017x; 1.5142x over previous
//
#include <hip/hip_runtime.h>
#include <hip/hip_bf16.h>

#define CDIM 192
#define WSZ 7
#define SSZ 3
#define NHEAD 6
#define HD 32
#define NTOK 49          // tokens per window
#define HW 56
#define TTOK (32*56*56)  // 100352 tokens total

typedef __attribute__((ext_vector_type(8))) short bf16x8;
typedef __attribute__((ext_vector_type(4))) float f32x4;

__device__ inline ushort f2bf(float v) {
    union { float f; unsigned u; } x; x.f = v;
    unsigned r = x.u + 0x7fff + ((x.u >> 16) & 1);
    return (ushort)(r >> 16);
}

__device__ inline float gelu_f(float x) {
    float t = 0.7978845608028654f * x * (1.0f + 0.044715f * x * x);
    float e = __expf(-2.0f * t);
    return 0.5f * x * (1.0f + (1.0f - e) / (1.0f + e));
}

// ---------------------------------------------------------------------------
// LayerNorm stats: one wave per token, 4 tokens per 256-thread block.
// ---------------------------------------------------------------------------
__global__ __launch_bounds__(256) void ln_stats_kernel(const float* __restrict__ x,
                                                       float2* __restrict__ stats) {
    int wid  = threadIdx.x >> 6;
    int lane = threadIdx.x & 63;
    int token = blockIdx.x * 4 + wid;
    const float* p = x + (size_t)token * CDIM;
    float a0 = p[lane], a1 = p[lane + 64], a2 = p[lane + 128];
    float s = a0 + a1 + a2;
    float q = a0 * a0 + a1 * a1 + a2 * a2;
    #pragma unroll
    for (int m = 32; m >= 1; m >>= 1) {
        s += __shfl_xor(s, m);
        q += __shfl_xor(q, m);
    }
    if (lane == 0) {
        float mean = s * (1.0f / 192.0f);
        float var  = q * (1.0f / 192.0f) - mean * mean;
        stats[token] = make_float2(mean, rsqrtf(var + 1e-5f));
    }
}

// ---------------------------------------------------------------------------
// Weight prep: bf16 N-major transposes for all GEMM B-operands.
// ---------------------------------------------------------------------------
__global__ __launch_bounds__(256) void prep_weights_kernel(
    const float* __restrict__ fc1_w, const float* __restrict__ fc2_w,
    const float* __restrict__ qkv_w, const float* __restrict__ proj_w,
    ushort* __restrict__ W1T, ushort* __restrict__ W2T,
    ushort* __restrict__ WqkvT, ushort* __restrict__ PjT) {
    int idx = blockIdx.x * 256 + threadIdx.x;  // grid covers exactly 147456
    {
        int n = idx / 192, k = idx - n * 192;
        W1T[idx] = f2bf(fc1_w[k * 768 + n]);
    }
    {
        int c = idx / 768, k = idx - c * 768;
        W2T[idx] = f2bf(fc2_w[k * 192 + c]);
    }
    if (idx < 576 * 192) {
        int n = idx / 192, k = idx - n * 192;
        WqkvT[idx] = f2bf(qkv_w[k * 576 + n]);
    }
    if (idx < 192 * 192) {
        int n = idx / 192, k = idx - n * 192;
        PjT[idx] = f2bf(proj_w[k * 192 + n]);
    }
}

// ---------------------------------------------------------------------------
// MFMA shifted-window attention + proj + residual (unchanged from round 2).
// ---------------------------------------------------------------------------
__global__ __launch_bounds__(256) void attn_mfma_kernel(
    const float*  __restrict__ x,
    const float2* __restrict__ stats,
    const float*  __restrict__ g1, const float* __restrict__ b1,
    const ushort* __restrict__ WqkvT, const float* __restrict__ qkv_b,
    const float*  __restrict__ rpb,
    const ushort* __restrict__ PjT, const float* __restrict__ proj_b,
    float* __restrict__ x2)
{
    __shared__ ushort A[64 * 200];
    __shared__ ushort Qs[64 * 40];
    __shared__ ushort Ks[64 * 40];
    __shared__ ushort Vs[32 * 72];
    __shared__ ushort Ps[64 * 72];
    __shared__ ushort Ho[64 * 40];
    __shared__ float  rpbl[169 * 6];
    __shared__ float  qbl[576];

    const int bid = blockIdx.x;
    const int b   = bid >> 6;
    const int w   = bid & 63;
    const int wh  = w >> 3, ww = w & 7;
    const int tid = threadIdx.x;
    const int l   = tid & 63;
    const int wid = tid >> 6;

    for (int e = tid; e < 169 * 6; e += 256) rpbl[e] = rpb[e];
    if (tid < 576 - 256) qbl[512 + tid] = qkv_b[512 + tid];
    qbl[tid] = qkv_b[tid];
    qbl[256 + tid] = qkv_b[256 + tid];

    {
        int n  = tid >> 2;
        int c0 = (tid & 3) * 48;
        if (n < NTOK) {
            int i = n / 7, j = n - i * 7;
            int hs = wh * 7 + i + SSZ; if (hs >= HW) hs -= HW;
            int ws = ww * 7 + j + SSZ; if (ws >= HW) ws -= HW;
            size_t tok = ((size_t)b * HW + hs) * HW + ws;
            float2 st = stats[tok];
            const float4* xr = (const float4*)(x + tok * CDIM + c0);
            const float4* gg = (const float4*)(g1 + c0);
            const float4* bb = (const float4*)(b1 + c0);
            #pragma unroll
            for (int j4 = 0; j4 < 12; j4++) {
                float4 v = xr[j4], g = gg[j4], bv = bb[j4];
                int c = n * 200 + c0 + j4 * 4;
                A[c + 0] = f2bf((v.x - st.x) * st.y * g.x + bv.x);
                A[c + 1] = f2bf((v.y - st.x) * st.y * g.y + bv.y);
                A[c + 2] = f2bf((v.z - st.x) * st.y * g.z + bv.z);
                A[c + 3] = f2bf((v.w - st.x) * st.y * g.w + bv.w);
            }
        } else {
            #pragma unroll
            for (int j4 = 0; j4 < 12; j4++) {
                int c = n * 200 + c0 + j4 * 4;
                A[c + 0] = 0; A[c + 1] = 0; A[c + 2] = 0; A[c + 3] = 0;
            }
        }
    }
    __syncthreads();

    const int lrow = l & 15;
    const int rg   = l >> 4;
    const int kg   = rg * 8;
    const int m0   = wid * 16;
    const int arow = m0 + lrow;
    const float scale = 0.17677669529663687f;

    bf16x8 a1[6];
    #pragma unroll
    for (int ks = 0; ks < 6; ks++)
        a1[ks] = *(const bf16x8*)&A[arow * 200 + ks * 32 + kg];

    int   rpi16[4][4];
    float madd[4][4];
    #pragma unroll
    for (int jj = 0; jj < 4; jj++) {
        int i  = m0 + rg * 4 + jj;
        int ih = (i * 9363) >> 16, iw = i - ih * 7;
        int pi = wh * 7 + ih, qi = ww * 7 + iw;
        int ci = (pi < 49 ? 0 : (pi < 53 ? 1 : 2)) * 3 + (qi < 49 ? 0 : (qi < 53 ? 1 : 2));
        #pragma unroll
        for (int nt = 0; nt < 4; nt++) {
            int j  = nt * 16 + lrow;
            int jh = (j * 9363) >> 16, jw = j - jh * 7;
            int pj = wh * 7 + jh, qj = ww * 7 + jw;
            int cj = (pj < 49 ? 0 : (pj < 53 ? 1 : 2)) * 3 + (qj < 49 ? 0 : (qj < 53 ? 1 : 2));
            int rpi = (ih - jh + 6) * 13 + (iw - jw + 6);
            rpi = rpi < 0 ? 0 : (rpi > 168 ? 168 : rpi);
            rpi16[jj][nt] = rpi * 6;
            madd[jj][nt] = (j >= NTOK) ? -1e30f : ((ci != cj) ? -100.0f : 0.0f);
        }
    }

    f32x4 acc2[12];
    #pragma unroll
    for (int i = 0; i < 12; i++) acc2[i] = (f32x4){0.f, 0.f, 0.f, 0.f};

    for (int h = 0; h < NHEAD; h++) {
        __syncthreads();

        #pragma unroll
        for (int t = 0; t < 6; t++) {
            const int nglob = (t >> 1) * 192 + h * 32 + (t & 1) * 16;
            f32x4 a = (f32x4){0.f, 0.f, 0.f, 0.f};
            const ushort* bp = WqkvT + (size_t)(nglob + lrow) * 192 + kg;
            #pragma unroll
            for (int ks = 0; ks < 6; ks++) {
                bf16x8 bfr = *(const bf16x8*)(bp + ks * 32 * sizeof(ushort) / 2);
                a = __builtin_amdgcn_mfma_f32_16x16x32_bf16(a1[ks], bfr, a, 0, 0, 0);
            }
            float bias = qbl[nglob + lrow];
            const int dl = (t & 1) * 16 + lrow;
            if (t < 2) {
                #pragma unroll
                for (int jj = 0; jj < 4; jj++)
                    Qs[(m0 + rg * 4 + jj) * 40 + dl] = f2bf((a[jj] + bias) * scale);
            } else if (t < 4) {
                #pragma unroll
                for (int jj = 0; jj < 4; jj++)
                    Ks[(m0 + rg * 4 + jj) * 40 + dl] = f2bf(a[jj] + bias);
            } else {
                #pragma unroll
                for (int jj = 0; jj < 4; jj++)
                    Vs[dl * 72 + m0 + rg * 4 + jj] = f2bf(a[jj] + bias);
            }
        }
        __syncthreads();

        bf16x8 aq = *(const bf16x8*)&Qs[arow * 40 + kg];
        f32x4 s4[4];
        #pragma unroll
        for (int nt = 0; nt < 4; nt++) {
            bf16x8 bk = *(const bf16x8*)&Ks[(nt * 16 + lrow) * 40 + kg];
            f32x4 a = (f32x4){0.f, 0.f, 0.f, 0.f};
            a = __builtin_amdgcn_mfma_f32_16x16x32_bf16(aq, bk, a, 0, 0, 0);
            #pragma unroll
            for (int jj = 0; jj < 4; jj++)
                s4[nt][jj] = a[jj] + rpbl[rpi16[jj][nt] + h] + madd[jj][nt];
        }

        #pragma unroll
        for (int jj = 0; jj < 4; jj++) {
            float m = fmaxf(fmaxf(s4[0][jj], s4[1][jj]), fmaxf(s4[2][jj], s4[3][jj]));
            #pragma unroll
            for (int msk = 1; msk < 16; msk <<= 1) m = fmaxf(m, __shfl_xor(m, msk));
            float e0 = __expf(s4[0][jj] - m);
            float e1 = __expf(s4[1][jj] - m);
            float e2 = __expf(s4[2][jj] - m);
            float e3 = __expf(s4[3][jj] - m);
            float r = e0 + e1 + e2 + e3;
            #pragma unroll
            for (int msk = 1; msk < 16; msk <<= 1) r += __shfl_xor(r, msk);
            float inv = 1.0f / r;
            int prow = (m0 + rg * 4 + jj) * 72;
            Ps[prow +  0 + lrow] = f2bf(e0 * inv);
            Ps[prow + 16 + lrow] = f2bf(e1 * inv);
            Ps[prow + 32 + lrow] = f2bf(e2 * inv);
            Ps[prow + 48 + lrow] = f2bf(e3 * inv);
        }

        #pragma unroll
        for (int nt = 0; nt < 2; nt++) {
            f32x4 a = (f32x4){0.f, 0.f, 0.f, 0.f};
            #pragma unroll
            for (int ks = 0; ks < 2; ks++) {
                bf16x8 pa = *(const bf16x8*)&Ps[arow * 72 + ks * 32 + kg];
                bf16x8 bv = *(const bf16x8*)&Vs[(nt * 16 + lrow) * 72 + ks * 32 + kg];
                a = __builtin_amdgcn_mfma_f32_16x16x32_bf16(pa, bv, a, 0, 0, 0);
            }
            #pragma unroll
            for (int jj = 0; jj < 4; jj++)
                Ho[(m0 + rg * 4 + jj) * 40 + nt * 16 + lrow] = f2bf(a[jj]);
        }

        bf16x8 ah = *(const bf16x8*)&Ho[arow * 40 + kg];
        #pragma unroll
        for (int nt = 0; nt < 12; nt++) {
            bf16x8 bp2 = *(const bf16x8*)&PjT[(size_t)(nt * 16 + lrow) * 192 + h * 32 + kg];
            acc2[nt] = __builtin_amdgcn_mfma_f32_16x16x32_bf16(ah, bp2, acc2[nt], 0, 0, 0);
        }
    }

    size_t gbase[4];
    int    valid[4];
    #pragma unroll
    for (int jj = 0; jj < 4; jj++) {
        int n = m0 + rg * 4 + jj;
        valid[jj] = (n < NTOK);
        int i = (n * 9363) >> 16, j = n - i * 7;
        int hs = wh * 7 + i + SSZ; if (hs >= HW) hs -= HW;
        int ws = ww * 7 + j + SSZ; if (ws >= HW) ws -= HW;
        gbase[jj] = (((size_t)b * HW + hs) * HW + ws) * CDIM;
    }
    #pragma unroll
    for (int nt = 0; nt < 12; nt++) {
        int c = nt * 16 + lrow;
        float pb = proj_b[c];
        #pragma unroll
        for (int jj = 0; jj < 4; jj++) {
            if (valid[jj])
                x2[gbase[jj] + c] = x[gbase[jj] + c] + pb + acc2[nt][jj];
        }
    }
}

// ---------------------------------------------------------------------------
// MFMA MLP v2: N split across waves (B-frags deduplicated, 4:1 MFMA:load),
// hidden chunk 384 (2 chunks, 4 barriers). LDS 75.8 KB -> 2 blocks/CU.
// Wave w: GEMM1 cols [w*96, w*96+96) per chunk; GEMM2 cols [w*48, w*48+48).
// ---------------------------------------------------------------------------
__global__ __launch_bounds__(256) void mlp_mfma_kernel(
    const float*  __restrict__ x2,
    const float2* __restrict__ stats,
    const float*  __restrict__ g2, const float* __restrict__ b2,
    const ushort* __restrict__ W1T, const float* __restrict__ fc1_b,
    const ushort* __restrict__ W2T, const float* __restrict__ fc2_b,
    float* __restrict__ out)
{
    __shared__ ushort A[64 * 200];    // 25600 B
    __shared__ ushort Hs[64 * 392];   // 50176 B  (pitch 392: 2-way banks, 16B rows)

    const int tid = threadIdx.x;
    const int l   = tid & 63;
    const int wid = tid >> 6;
    const size_t tok0 = (size_t)blockIdx.x * 64;

    // ---- stage LN2(x2) tile as bf16 ----
    {
        int n  = tid >> 2;
        int c0 = (tid & 3) * 48;
        size_t tok = tok0 + n;
        float2 st = stats[tok];
        const float4* xr = (const float4*)(x2 + tok * CDIM + c0);
        const float4* gg = (const float4*)(g2 + c0);
        const float4* bb = (const float4*)(b2 + c0);
        #pragma unroll
        for (int j4 = 0; j4 < 12; j4++) {
            float4 v = xr[j4], g = gg[j4], b = bb[j4];
            int c = n * 200 + c0 + j4 * 4;
            A[c + 0] = f2bf((v.x - st.x) * st.y * g.x + b.x);
            A[c + 1] = f2bf((v.y - st.x) * st.y * g.y + b.y);
            A[c + 2] = f2bf((v.z - st.x) * st.y * g.z + b.z);
            A[c + 3] = f2bf((v.w - st.x) * st.y * g.w + b.w);
        }
    }
    __syncthreads();

    const int lrow = l & 15;
    const int rg   = l >> 4;
    const int kg   = rg * 8;

    f32x4 acc2[3][4];
    #pragma unroll
    for (int nt = 0; nt < 3; nt++)
        #pragma unroll
        for (int m = 0; m < 4; m++) acc2[nt][m] = (f32x4){0.f, 0.f, 0.f, 0.f};

    for (int ch = 0; ch < 2; ch++) {
        const int h0 = ch * 384;
        if (ch) __syncthreads();   // prior GEMM2 reads of Hs complete

        // A-frags for all 4 M-tiles (re-read per chunk to bound VGPR)
        bf16x8 a1[4][6];
        #pragma unroll
        for (int m = 0; m < 4; m++)
            #pragma unroll
            for (int ks = 0; ks < 6; ks++)
                a1[m][ks] = *(const bf16x8*)&A[(m * 16 + lrow) * 200 + ks * 32 + kg];

        // ---- GEMM1: H[:, wave slice] = gelu(A @ W1 + b1) ----
        #pragma unroll
        for (int nt = 0; nt < 6; nt++) {
            const int ncol  = wid * 96 + nt * 16;     // col within chunk
            const int nglob = h0 + ncol;
            const ushort* bp = W1T + (size_t)(nglob + lrow) * 192 + kg;
            bf16x8 bfr[6];
            #pragma unroll
            for (int ks = 0; ks < 6; ks++)
                bfr[ks] = *(const bf16x8*)(bp + ks * 32);
            float bias = fc1_b[nglob + lrow];
            #pragma unroll
            for (int m = 0; m < 4; m++) {
                f32x4 a = (f32x4){0.f, 0.f, 0.f, 0.f};
                #pragma unroll
                for (int ks = 0; ks < 6; ks++)
                    a = __builtin_amdgcn_mfma_f32_16x16x32_bf16(a1[m][ks], bfr[ks], a, 0, 0, 0);
                #pragma unroll
                for (int jj = 0; jj < 4; jj++)
                    Hs[(m * 16 + rg * 4 + jj) * 392 + ncol + lrow] = f2bf(gelu_f(a[jj] + bias));
            }
        }
        __syncthreads();

        // ---- GEMM2: acc2 += H_chunk @ W2[h0:h0+384, wave slice] ----
        #pragma unroll
        for (int ksb = 0; ksb < 3; ksb++) {
            const int kb = ksb * 128;
            bf16x8 b2f[3][4];
            #pragma unroll
            for (int nt = 0; nt < 3; nt++) {
                const ushort* bp = W2T + (size_t)(wid * 48 + nt * 16 + lrow) * 768 + h0 + kb + kg;
                #pragma unroll
                for (int ks = 0; ks < 4; ks++)
                    b2f[nt][ks] = *(const bf16x8*)(bp + ks * 32);
            }
            bf16x8 aH[4][4];
            #pragma unroll
            for (int m = 0; m < 4; m++)
                #pragma unroll
                for (int ks = 0; ks < 4; ks++)
                    aH[m][ks] = *(const bf16x8*)&Hs[(m * 16 + lrow) * 392 + kb + ks * 32 + kg];
            #pragma unroll
            for (int nt = 0; nt < 3; nt++)
                #pragma unroll
                for (int m = 0; m < 4; m++)
                    #pragma unroll
                    for (int ks = 0; ks < 4; ks++)
                        acc2[nt][m] = __builtin_amdgcn_mfma_f32_16x16x32_bf16(
                            aH[m][ks], b2f[nt][ks], acc2[nt][m], 0, 0, 0);
        }
    }

    // ---- epilogue: out = x2 + acc2 + fc2_b ----
    #pragma unroll
    for (int nt = 0; nt < 3; nt++) {
        int c = wid * 48 + nt * 16 + lrow;
        float fb = fc2_b[c];
        #pragma unroll
        for (int m = 0; m < 4; m++) {
            #pragma unroll
            for (int jj = 0; jj < 4; jj++) {
                size_t tok = tok0 + m * 16 + rg * 4 + jj;
                out[tok * CDIM + c] = x2[tok * CDIM + c] + acc2[nt][m][jj] + fb;
            }
        }
    }
}

// ---------------------------------------------------------------------------
extern "C" void kernel_launch(void* const* d_in, const int* in_sizes, int n_in,
                              void* d_out, int out_size, void* d_ws, size_t ws_size,
                              hipStream_t stream) {
    const float* x      = (const float*)d_in[0];
    const float* g1     = (const float*)d_in[1];
    const float* b1     = (const float*)d_in[2];
    const float* qkv_w  = (const float*)d_in[3];
    const float* qkv_b  = (const float*)d_in[4];
    const float* rpb    = (const float*)d_in[5];
    const float* proj_w = (const float*)d_in[6];
    const float* proj_b = (const float*)d_in[7];
    const float* g2     = (const float*)d_in[8];
    const float* b2     = (const float*)d_in[9];
    const float* fc1_w  = (const float*)d_in[10];
    const float* fc1_b  = (const float*)d_in[11];
    const float* fc2_w  = (const float*)d_in[12];
    const float* fc2_b  = (const float*)d_in[13];
    float* out = (float*)d_out;

    char* ws = (char*)d_ws;
    float2* stats1 = (float2*)ws;                     //   802816 B
    float2* stats2 = (float2*)(ws + 802816);          //   802816 B
    float*  x2     = (float*)(ws + 1605632);          // 77070336 B
    ushort* W1T    = (ushort*)(ws + 78675968);        //   294912 B
    ushort* W2T    = (ushort*)(ws + 78970880);        //   294912 B
    ushort* WqkvT  = (ushort*)(ws + 79265792);        //   221184 B
    ushort* PjT    = (ushort*)(ws + 79486976);        //    73728 B

    ln_stats_kernel<<<TTOK / 4, 256, 0, stream>>>(x, stats1);
    prep_weights_kernel<<<576, 256, 0, stream>>>(fc1_w, fc2_w, qkv_w, proj_w,
                                                 W1T, W2T, WqkvT, PjT);
    attn_mfma_kernel<<<32 * 64, 256, 0, stream>>>(x, stats1, g1, b1,
                                                  WqkvT, qkv_b, rpb,
                                                  PjT, proj_b, x2);
    ln_stats_kernel<<<TTOK / 4, 256, 0, stream>>>(x2, stats2);
    mlp_mfma_kernel<<<TTOK / 64, 256, 0, stream>>>(x2, stats2, g2, b2,
                                                   W1T, fc1_b, W2T, fc2_b, out);
}

// Round 5
// 359.451 us; speedup vs baseline: 27.0582x; 1.7016x over previous
//
#include <hip/hip_runtime.h>
#include <hip/hip_bf16.h>

#define CDIM 192
#define WSZ 7
#define SSZ 3
#define NHEAD 6
#define HD 32
#define NTOK 49          // tokens per window
#define HW 56
#define TTOK (32*56*56)  // 100352 tokens total

typedef __attribute__((ext_vector_type(8))) short bf16x8;
typedef __attribute__((ext_vector_type(4))) float f32x4;

__device__ inline ushort f2bf(float v) {
    union { float f; unsigned u; } x; x.f = v;
    unsigned r = x.u + 0x7fff + ((x.u >> 16) & 1);
    return (ushort)(r >> 16);
}

__device__ inline float gelu_f(float x) {
    float t = 0.7978845608028654f * x * (1.0f + 0.044715f * x * x);
    float e = __expf(-2.0f * t);
    return 0.5f * x * (1.0f + (1.0f - e) / (1.0f + e));
}

// ---------------------------------------------------------------------------
// LayerNorm stats: one wave per token, 4 tokens per 256-thread block.
// ---------------------------------------------------------------------------
__global__ __launch_bounds__(256) void ln_stats_kernel(const float* __restrict__ x,
                                                       float2* __restrict__ stats) {
    int wid  = threadIdx.x >> 6;
    int lane = threadIdx.x & 63;
    int token = blockIdx.x * 4 + wid;
    const float* p = x + (size_t)token * CDIM;
    float a0 = p[lane], a1 = p[lane + 64], a2 = p[lane + 128];
    float s = a0 + a1 + a2;
    float q = a0 * a0 + a1 * a1 + a2 * a2;
    #pragma unroll
    for (int m = 32; m >= 1; m >>= 1) {
        s += __shfl_xor(s, m);
        q += __shfl_xor(q, m);
    }
    if (lane == 0) {
        float mean = s * (1.0f / 192.0f);
        float var  = q * (1.0f / 192.0f) - mean * mean;
        stats[token] = make_float2(mean, rsqrtf(var + 1e-5f));
    }
}

// ---------------------------------------------------------------------------
// Weight prep: bf16 N-major transposes for all GEMM B-operands.
// ---------------------------------------------------------------------------
__global__ __launch_bounds__(256) void prep_weights_kernel(
    const float* __restrict__ fc1_w, const float* __restrict__ fc2_w,
    const float* __restrict__ qkv_w, const float* __restrict__ proj_w,
    ushort* __restrict__ W1T, ushort* __restrict__ W2T,
    ushort* __restrict__ WqkvT, ushort* __restrict__ PjT) {
    int idx = blockIdx.x * 256 + threadIdx.x;  // grid covers exactly 147456
    {
        int n = idx / 192, k = idx - n * 192;
        W1T[idx] = f2bf(fc1_w[k * 768 + n]);
    }
    {
        int c = idx / 768, k = idx - c * 768;
        W2T[idx] = f2bf(fc2_w[k * 192 + c]);
    }
    if (idx < 576 * 192) {
        int n = idx / 192, k = idx - n * 192;
        WqkvT[idx] = f2bf(qkv_w[k * 576 + n]);
    }
    if (idx < 192 * 192) {
        int n = idx / 192, k = idx - n * 192;
        PjT[idx] = f2bf(proj_w[k * 192 + n]);
    }
}

// ---------------------------------------------------------------------------
// MFMA shifted-window attention v2: head-pair loop, N-split QKV and proj
// (B-frags loaded once per wave, reused across 4 M-tiles), M-split
// scores/softmax/PV. 2 barriers per pair. LDS 75.7 KB -> 2 blocks/CU.
// ---------------------------------------------------------------------------
__global__ __launch_bounds__(256, 2) void attn_mfma_kernel(
    const float*  __restrict__ x,
    const float2* __restrict__ stats,
    const float*  __restrict__ g1, const float* __restrict__ b1,
    const ushort* __restrict__ WqkvT, const float* __restrict__ qkv_b,
    const float*  __restrict__ rpb,
    const ushort* __restrict__ PjT, const float* __restrict__ proj_b,
    float* __restrict__ x2)
{
    __shared__ ushort A[64 * 200];    // 25600 B  LN'd tokens (rows 49-63 zero)
    __shared__ ushort Qs[64 * 72];    //  9216 B  q scaled, [tok][pairdim]
    __shared__ ushort Ks[64 * 72];    //  9216 B  k, [tok][pairdim]
    __shared__ ushort Vs[64 * 72];    //  9216 B  v, [pairdim][tok]
    __shared__ ushort Ps[64 * 72];    //  9216 B  P, [tok][kv] (wave-private rows)
    __shared__ ushort Ho[64 * 72];    //  9216 B  head-pair out, [tok][pairdim]
    __shared__ float  rpbl[169 * 6];  //  4056 B   -> 75736 B total

    const int bid = blockIdx.x;
    const int b   = bid >> 6;
    const int w   = bid & 63;
    const int wh  = w >> 3, ww = w & 7;
    const int tid = threadIdx.x;
    const int l   = tid & 63;
    const int wid = tid >> 6;

    for (int e = tid; e < 169 * 6; e += 256) rpbl[e] = rpb[e];

    // ---- stage A = LN1(x window, shifted), bf16; pad rows zero ----
    {
        int n  = tid >> 2;
        int c0 = (tid & 3) * 48;
        if (n < NTOK) {
            int i = n / 7, j = n - i * 7;
            int hs = wh * 7 + i + SSZ; if (hs >= HW) hs -= HW;
            int ws = ww * 7 + j + SSZ; if (ws >= HW) ws -= HW;
            size_t tok = ((size_t)b * HW + hs) * HW + ws;
            float2 st = stats[tok];
            const float4* xr = (const float4*)(x + tok * CDIM + c0);
            const float4* gg = (const float4*)(g1 + c0);
            const float4* bb = (const float4*)(b1 + c0);
            #pragma unroll
            for (int j4 = 0; j4 < 12; j4++) {
                float4 v = xr[j4], g = gg[j4], bv = bb[j4];
                int c = n * 200 + c0 + j4 * 4;
                A[c + 0] = f2bf((v.x - st.x) * st.y * g.x + bv.x);
                A[c + 1] = f2bf((v.y - st.x) * st.y * g.y + bv.y);
                A[c + 2] = f2bf((v.z - st.x) * st.y * g.z + bv.z);
                A[c + 3] = f2bf((v.w - st.x) * st.y * g.w + bv.w);
            }
        } else {
            #pragma unroll
            for (int j4 = 0; j4 < 12; j4++) {
                int c = n * 200 + c0 + j4 * 4;
                A[c + 0] = 0; A[c + 1] = 0; A[c + 2] = 0; A[c + 3] = 0;
            }
        }
    }
    __syncthreads();

    const int lrow = l & 15;
    const int rg   = l >> 4;
    const int kg   = rg * 8;
    const int m0   = wid * 16;
    const int arow = m0 + lrow;
    const float scale = 0.17677669529663687f;

    // per-lane bias/mask tables (head-independent): score[i=m0+rg*4+jj][j=nt*16+lrow]
    int   rpi16[4][4];
    float madd[4][4];
    #pragma unroll
    for (int jj = 0; jj < 4; jj++) {
        int i  = m0 + rg * 4 + jj;
        int ih = (i * 9363) >> 16, iw = i - ih * 7;
        int pi = wh * 7 + ih, qi = ww * 7 + iw;
        int ci = (pi < 49 ? 0 : (pi < 53 ? 1 : 2)) * 3 + (qi < 49 ? 0 : (qi < 53 ? 1 : 2));
        #pragma unroll
        for (int nt = 0; nt < 4; nt++) {
            int j  = nt * 16 + lrow;
            int jh = (j * 9363) >> 16, jw = j - jh * 7;
            int pj = wh * 7 + jh, qj = ww * 7 + jw;
            int cj = (pj < 49 ? 0 : (pj < 53 ? 1 : 2)) * 3 + (qj < 49 ? 0 : (qj < 53 ? 1 : 2));
            int rpi = (ih - jh + 6) * 13 + (iw - jw + 6);
            rpi = rpi < 0 ? 0 : (rpi > 168 ? 168 : rpi);
            rpi16[jj][nt] = rpi * 6;
            madd[jj][nt] = (j >= NTOK) ? -1e30f : ((ci != cj) ? -100.0f : 0.0f);
        }
    }

    f32x4 acc2[3][4];   // proj: [n-tile][m-tile], wave owns cols wid*48..+48
    #pragma unroll
    for (int nt = 0; nt < 3; nt++)
        #pragma unroll
        for (int m = 0; m < 4; m++) acc2[nt][m] = (f32x4){0.f, 0.f, 0.f, 0.f};

    for (int p = 0; p < 3; p++) {
        const int h0 = p * 2;

        // A-frags for all 4 M-tiles (re-read per pair: short live range)
        bf16x8 a1[4][6];
        #pragma unroll
        for (int m = 0; m < 4; m++)
            #pragma unroll
            for (int ks = 0; ks < 6; ks++)
                a1[m][ks] = *(const bf16x8*)&A[(m * 16 + lrow) * 200 + ks * 32 + kg];

        // ---- QKV, N-split: wave handles 3 of 12 tiles; B reused over 4 M ----
        #pragma unroll
        for (int tt = 0; tt < 3; tt++) {
            const int t    = wid * 3 + tt;
            const int kind = t >> 2;          // 0=Q 1=K 2=V (wave-uniform)
            const int sub  = t & 3;
            const int hh   = sub >> 1, half = sub & 1;
            const int dim2 = hh * 32 + half * 16 + lrow;  // pair-local out dim
            const int nglob = kind * 192 + (h0 + hh) * 32 + half * 16;
            const ushort* bp = WqkvT + (size_t)(nglob + lrow) * 192 + kg;
            bf16x8 bfr[6];
            #pragma unroll
            for (int ks = 0; ks < 6; ks++)
                bfr[ks] = *(const bf16x8*)(bp + ks * 32);
            float bias = qkv_b[nglob + lrow];
            #pragma unroll
            for (int m = 0; m < 4; m++) {
                f32x4 a = (f32x4){0.f, 0.f, 0.f, 0.f};
                #pragma unroll
                for (int ks = 0; ks < 6; ks++)
                    a = __builtin_amdgcn_mfma_f32_16x16x32_bf16(a1[m][ks], bfr[ks], a, 0, 0, 0);
                #pragma unroll
                for (int jj = 0; jj < 4; jj++) {
                    int tok = m * 16 + rg * 4 + jj;
                    float v = a[jj] + bias;
                    if (kind == 0)      Qs[tok * 72 + dim2] = f2bf(v * scale);
                    else if (kind == 1) Ks[tok * 72 + dim2] = f2bf(v);
                    else                Vs[dim2 * 72 + tok] = f2bf(v);
                }
            }
        }
        __syncthreads();   // Q/K/V staged (also: prior proj reads done before new Ho)

        // ---- per head: scores + softmax + PV (wave-local M-band) ----
        #pragma unroll
        for (int hh = 0; hh < 2; hh++) {
            const int h = h0 + hh;
            bf16x8 aq = *(const bf16x8*)&Qs[arow * 72 + hh * 32 + kg];
            f32x4 s4[4];
            #pragma unroll
            for (int nt = 0; nt < 4; nt++) {
                bf16x8 bk = *(const bf16x8*)&Ks[(nt * 16 + lrow) * 72 + hh * 32 + kg];
                f32x4 a = (f32x4){0.f, 0.f, 0.f, 0.f};
                a = __builtin_amdgcn_mfma_f32_16x16x32_bf16(aq, bk, a, 0, 0, 0);
                #pragma unroll
                for (int jj = 0; jj < 4; jj++)
                    s4[nt][jj] = a[jj] + rpbl[rpi16[jj][nt] + h] + madd[jj][nt];
            }

            #pragma unroll
            for (int jj = 0; jj < 4; jj++) {
                float m = fmaxf(fmaxf(s4[0][jj], s4[1][jj]), fmaxf(s4[2][jj], s4[3][jj]));
                #pragma unroll
                for (int msk = 1; msk < 16; msk <<= 1) m = fmaxf(m, __shfl_xor(m, msk));
                float e0 = __expf(s4[0][jj] - m);
                float e1 = __expf(s4[1][jj] - m);
                float e2 = __expf(s4[2][jj] - m);
                float e3 = __expf(s4[3][jj] - m);
                float r = e0 + e1 + e2 + e3;
                #pragma unroll
                for (int msk = 1; msk < 16; msk <<= 1) r += __shfl_xor(r, msk);
                float inv = 1.0f / r;
                int prow = (m0 + rg * 4 + jj) * 72;
                Ps[prow +  0 + lrow] = f2bf(e0 * inv);
                Ps[prow + 16 + lrow] = f2bf(e1 * inv);
                Ps[prow + 32 + lrow] = f2bf(e2 * inv);
                Ps[prow + 48 + lrow] = f2bf(e3 * inv);
            }

            #pragma unroll
            for (int nt = 0; nt < 2; nt++) {
                f32x4 a = (f32x4){0.f, 0.f, 0.f, 0.f};
                #pragma unroll
                for (int ks = 0; ks < 2; ks++) {
                    bf16x8 pa = *(const bf16x8*)&Ps[arow * 72 + ks * 32 + kg];
                    bf16x8 bv = *(const bf16x8*)&Vs[(hh * 32 + nt * 16 + lrow) * 72 + ks * 32 + kg];
                    a = __builtin_amdgcn_mfma_f32_16x16x32_bf16(pa, bv, a, 0, 0, 0);
                }
                #pragma unroll
                for (int jj = 0; jj < 4; jj++)
                    Ho[(m0 + rg * 4 + jj) * 72 + hh * 32 + nt * 16 + lrow] = f2bf(a[jj]);
            }
        }
        __syncthreads();   // Ho staged for cross-wave proj reads

        // ---- proj, N-split: acc2 += Ho @ PjT[pair k-slice, wave cols] ----
        bf16x8 aH[4][2];
        #pragma unroll
        for (int m = 0; m < 4; m++)
            #pragma unroll
            for (int ks = 0; ks < 2; ks++)
                aH[m][ks] = *(const bf16x8*)&Ho[(m * 16 + lrow) * 72 + ks * 32 + kg];
        #pragma unroll
        for (int nt = 0; nt < 3; nt++) {
            const ushort* bp = PjT + (size_t)(wid * 48 + nt * 16 + lrow) * 192 + p * 64 + kg;
            bf16x8 b0 = *(const bf16x8*)(bp);
            bf16x8 b1f = *(const bf16x8*)(bp + 32);
            #pragma unroll
            for (int m = 0; m < 4; m++) {
                acc2[nt][m] = __builtin_amdgcn_mfma_f32_16x16x32_bf16(aH[m][0], b0, acc2[nt][m], 0, 0, 0);
                acc2[nt][m] = __builtin_amdgcn_mfma_f32_16x16x32_bf16(aH[m][1], b1f, acc2[nt][m], 0, 0, 0);
            }
        }
    }

    // ---- epilogue: x2 = x + proj_out + proj_b (N-split cols, 49 rows) ----
    float pb[3];
    #pragma unroll
    for (int nt = 0; nt < 3; nt++) pb[nt] = proj_b[wid * 48 + nt * 16 + lrow];
    #pragma unroll
    for (int m = 0; m < 4; m++) {
        #pragma unroll
        for (int jj = 0; jj < 4; jj++) {
            int n = m * 16 + rg * 4 + jj;
            if (n < NTOK) {
                int i = (n * 9363) >> 16, j = n - i * 7;
                int hs = wh * 7 + i + SSZ; if (hs >= HW) hs -= HW;
                int ws = ww * 7 + j + SSZ; if (ws >= HW) ws -= HW;
                size_t gb = (((size_t)b * HW + hs) * HW + ws) * CDIM;
                #pragma unroll
                for (int nt = 0; nt < 3; nt++) {
                    int c = wid * 48 + nt * 16 + lrow;
                    x2[gb + c] = x[gb + c] + pb[nt] + acc2[nt][m][jj];
                }
            }
        }
    }
}

// ---------------------------------------------------------------------------
// MFMA MLP v2 (unchanged from round 3).
// ---------------------------------------------------------------------------
__global__ __launch_bounds__(256) void mlp_mfma_kernel(
    const float*  __restrict__ x2,
    const float2* __restrict__ stats,
    const float*  __restrict__ g2, const float* __restrict__ b2,
    const ushort* __restrict__ W1T, const float* __restrict__ fc1_b,
    const ushort* __restrict__ W2T, const float* __restrict__ fc2_b,
    float* __restrict__ out)
{
    __shared__ ushort A[64 * 200];    // 25600 B
    __shared__ ushort Hs[64 * 392];   // 50176 B

    const int tid = threadIdx.x;
    const int l   = tid & 63;
    const int wid = tid >> 6;
    const size_t tok0 = (size_t)blockIdx.x * 64;

    {
        int n  = tid >> 2;
        int c0 = (tid & 3) * 48;
        size_t tok = tok0 + n;
        float2 st = stats[tok];
        const float4* xr = (const float4*)(x2 + tok * CDIM + c0);
        const float4* gg = (const float4*)(g2 + c0);
        const float4* bb = (const float4*)(b2 + c0);
        #pragma unroll
        for (int j4 = 0; j4 < 12; j4++) {
            float4 v = xr[j4], g = gg[j4], b = bb[j4];
            int c = n * 200 + c0 + j4 * 4;
            A[c + 0] = f2bf((v.x - st.x) * st.y * g.x + b.x);
            A[c + 1] = f2bf((v.y - st.x) * st.y * g.y + b.y);
            A[c + 2] = f2bf((v.z - st.x) * st.y * g.z + b.z);
            A[c + 3] = f2bf((v.w - st.x) * st.y * g.w + b.w);
        }
    }
    __syncthreads();

    const int lrow = l & 15;
    const int rg   = l >> 4;
    const int kg   = rg * 8;

    f32x4 acc2[3][4];
    #pragma unroll
    for (int nt = 0; nt < 3; nt++)
        #pragma unroll
        for (int m = 0; m < 4; m++) acc2[nt][m] = (f32x4){0.f, 0.f, 0.f, 0.f};

    for (int ch = 0; ch < 2; ch++) {
        const int h0 = ch * 384;
        if (ch) __syncthreads();

        bf16x8 a1[4][6];
        #pragma unroll
        for (int m = 0; m < 4; m++)
            #pragma unroll
            for (int ks = 0; ks < 6; ks++)
                a1[m][ks] = *(const bf16x8*)&A[(m * 16 + lrow) * 200 + ks * 32 + kg];

        #pragma unroll
        for (int nt = 0; nt < 6; nt++) {
            const int ncol  = wid * 96 + nt * 16;
            const int nglob = h0 + ncol;
            const ushort* bp = W1T + (size_t)(nglob + lrow) * 192 + kg;
            bf16x8 bfr[6];
            #pragma unroll
            for (int ks = 0; ks < 6; ks++)
                bfr[ks] = *(const bf16x8*)(bp + ks * 32);
            float bias = fc1_b[nglob + lrow];
            #pragma unroll
            for (int m = 0; m < 4; m++) {
                f32x4 a = (f32x4){0.f, 0.f, 0.f, 0.f};
                #pragma unroll
                for (int ks = 0; ks < 6; ks++)
                    a = __builtin_amdgcn_mfma_f32_16x16x32_bf16(a1[m][ks], bfr[ks], a, 0, 0, 0);
                #pragma unroll
                for (int jj = 0; jj < 4; jj++)
                    Hs[(m * 16 + rg * 4 + jj) * 392 + ncol + lrow] = f2bf(gelu_f(a[jj] + bias));
            }
        }
        __syncthreads();

        #pragma unroll
        for (int ksb = 0; ksb < 3; ksb++) {
            const int kb = ksb * 128;
            bf16x8 b2f[3][4];
            #pragma unroll
            for (int nt = 0; nt < 3; nt++) {
                const ushort* bp = W2T + (size_t)(wid * 48 + nt * 16 + lrow) * 768 + h0 + kb + kg;
                #pragma unroll
                for (int ks = 0; ks < 4; ks++)
                    b2f[nt][ks] = *(const bf16x8*)(bp + ks * 32);
            }
            bf16x8 aH[4][4];
            #pragma unroll
            for (int m = 0; m < 4; m++)
                #pragma unroll
                for (int ks = 0; ks < 4; ks++)
                    aH[m][ks] = *(const bf16x8*)&Hs[(m * 16 + lrow) * 392 + kb + ks * 32 + kg];
            #pragma unroll
            for (int nt = 0; nt < 3; nt++)
                #pragma unroll
                for (int m = 0; m < 4; m++)
                    #pragma unroll
                    for (int ks = 0; ks < 4; ks++)
                        acc2[nt][m] = __builtin_amdgcn_mfma_f32_16x16x32_bf16(
                            aH[m][ks], b2f[nt][ks], acc2[nt][m], 0, 0, 0);
        }
    }

    #pragma unroll
    for (int nt = 0; nt < 3; nt++) {
        int c = wid * 48 + nt * 16 + lrow;
        float fb = fc2_b[c];
        #pragma unroll
        for (int m = 0; m < 4; m++) {
            #pragma unroll
            for (int jj = 0; jj < 4; jj++) {
                size_t tok = tok0 + m * 16 + rg * 4 + jj;
                out[tok * CDIM + c] = x2[tok * CDIM + c] + acc2[nt][m][jj] + fb;
            }
        }
    }
}

// ---------------------------------------------------------------------------
extern "C" void kernel_launch(void* const* d_in, const int* in_sizes, int n_in,
                              void* d_out, int out_size, void* d_ws, size_t ws_size,
                              hipStream_t stream) {
    const float* x      = (const float*)d_in[0];
    const float* g1     = (const float*)d_in[1];
    const float* b1     = (const float*)d_in[2];
    const float* qkv_w  = (const float*)d_in[3];
    const float* qkv_b  = (const float*)d_in[4];
    const float* rpb    = (const float*)d_in[5];
    const float* proj_w = (const float*)d_in[6];
    const float* proj_b = (const float*)d_in[7];
    const float* g2     = (const float*)d_in[8];
    const float* b2     = (const float*)d_in[9];
    const float* fc1_w  = (const float*)d_in[10];
    const float* fc1_b  = (const float*)d_in[11];
    const float* fc2_w  = (const float*)d_in[12];
    const float* fc2_b  = (const float*)d_in[13];
    float* out = (float*)d_out;

    char* ws = (char*)d_ws;
    float2* stats1 = (float2*)ws;                     //   802816 B
    float2* stats2 = (float2*)(ws + 802816);          //   802816 B
    float*  x2     = (float*)(ws + 1605632);          // 77070336 B
    ushort* W1T    = (ushort*)(ws + 78675968);        //   294912 B
    ushort* W2T    = (ushort*)(ws + 78970880);        //   294912 B
    ushort* WqkvT  = (ushort*)(ws + 79265792);        //   221184 B
    ushort* PjT    = (ushort*)(ws + 79486976);        //    73728 B

    ln_stats_kernel<<<TTOK / 4, 256, 0, stream>>>(x, stats1);
    prep_weights_kernel<<<576, 256, 0, stream>>>(fc1_w, fc2_w, qkv_w, proj_w,
                                                 W1T, W2T, WqkvT, PjT);
    attn_mfma_kernel<<<32 * 64, 256, 0, stream>>>(x, stats1, g1, b1,
                                                  WqkvT, qkv_b, rpb,
                                                  PjT, proj_b, x2);
    ln_stats_kernel<<<TTOK / 4, 256, 0, stream>>>(x2, stats2);
    mlp_mfma_kernel<<<TTOK / 64, 256, 0, stream>>>(x2, stats2, g2, b2,
                                                   W1T, fc1_b, W2T, fc2_b, out);
}